// Round 1
// baseline (1577.348 us; speedup 1.0000x reference)
//
#include <hip/hip_runtime.h>
#include <math.h>

#define BB   16
#define TFULL 4096
#define T2   2048
#define LSEQ 2019
#define CIN  64
#define CO   32
#define HD   64
#define NST  64
#define NLAY 8
#define DOUT 640
#define EPSF 1e-5f

static __device__ __forceinline__ float sigm(float x){ return 1.f/(1.f + __expf(-x)); }
static __device__ __forceinline__ float gelu_(float x){ return 0.5f*x*(1.f + erff(x*0.7071067811865475f)); }

// ---------------- Stage A: pw1 conv + GN1 partial stats ----------------
__global__ void __launch_bounds__(256) k_pw1(const float* __restrict__ x,
                                             const float* __restrict__ w,
                                             const float* __restrict__ bias,
                                             float* __restrict__ u1,
                                             float* __restrict__ stats){
  // grid: BB * (TFULL/64) = 1024 blocks
  int blk = blockIdx.x;
  int b  = blk >> 6;
  int t0 = (blk & 63) << 6;
  __shared__ float xs[CIN][64];
  __shared__ float wsm[CO*CIN];
  __shared__ float red[8];
  int tid = threadIdx.x;
  for (int i = tid; i < CIN*64; i += 256){
    int c = i >> 6, t = i & 63;
    xs[c][t] = x[((long)(b*CIN + c))*TFULL + t0 + t];
  }
  for (int i = tid; i < CO*CIN; i += 256) wsm[i] = w[i];
  __syncthreads();
  int t  = tid & 63;
  int o0 = tid >> 6;
  float lsum = 0.f, lsq = 0.f;
  for (int o = o0; o < CO; o += 4){
    float acc = bias[o];
    #pragma unroll
    for (int c = 0; c < CIN; ++c) acc = fmaf(wsm[o*CIN + c], xs[c][t], acc);
    u1[((long)(b*CO + o))*TFULL + t0 + t] = acc;
    lsum += acc; lsq += acc*acc;
  }
  #pragma unroll
  for (int off = 32; off; off >>= 1){ lsum += __shfl_down(lsum, off); lsq += __shfl_down(lsq, off); }
  if ((tid & 63) == 0){ red[tid>>6] = lsum; red[4 + (tid>>6)] = lsq; }
  __syncthreads();
  if (tid == 0){
    atomicAdd(&stats[b],      red[0]+red[1]+red[2]+red[3]);
    atomicAdd(&stats[16 + b], red[4]+red[5]+red[6]+red[7]);
  }
}

// ---------------- finalize GN stats (which=0 -> gn1, which=1 -> gn2) ----------------
__global__ void k_gnstat(float* __restrict__ stats, int which, float cnt){
  int b = threadIdx.x;
  if (b < BB){
    int o = which * 64;
    float m = stats[o + b] / cnt;
    float v = stats[o + 16 + b] / cnt - m*m;
    stats[o + 32 + b] = m;
    stats[o + 48 + b] = rsqrtf(v + EPSF);
  }
}

// ---------------- Stage A3: GN1 apply + GLU(time) + SiLU ----------------
__global__ void __launch_bounds__(256) k_glu_silu(const float* __restrict__ u1,
                                                  const float* __restrict__ g,
                                                  const float* __restrict__ bb,
                                                  const float* __restrict__ stats,
                                                  float* __restrict__ u2){
  // grid: BB * (T2/64) = 512
  int blk = blockIdx.x;
  int b  = blk >> 5;
  int t0 = (blk & 31) << 6;
  float m = stats[32 + b], r = stats[48 + b];
  int tid = threadIdx.x;
  int t = t0 + (tid & 63);
  for (int c = tid >> 6; c < CO; c += 4){
    long base = ((long)(b*CO + c))*TFULL;
    float a  = u1[base + t];
    float bv = u1[base + t + T2];
    float gc = g[c], bc = bb[c];
    a  = (a  - m)*r*gc + bc;
    bv = (bv - m)*r*gc + bc;
    float z = a * sigm(bv);
    z = z * sigm(z);
    u2[((long)(b*CO + c))*T2 + t] = z;
  }
}

// ---------------- Stage B1: depthwise conv (K=32, pad 1) + GN2 partial stats ----------------
__global__ void __launch_bounds__(256) k_dconv(const float* __restrict__ u2,
                                               const float* __restrict__ w,
                                               const float* __restrict__ bias,
                                               float* __restrict__ v,
                                               float* __restrict__ stats){
  // grid: BB*CO = 512 blocks, one (b,c) row each
  int blk = blockIdx.x;
  int b = blk >> 5, c = blk & 31;
  __shared__ float row[T2 + 2];
  __shared__ float red[8];
  int tid = threadIdx.x;
  if (tid == 0){ row[0] = 0.f; row[T2 + 1] = 0.f; }
  const float* src = u2 + ((long)(b*CO + c))*T2;
  for (int i = tid; i < T2; i += 256) row[1 + i] = src[i];
  __syncthreads();
  float wk[32];
  #pragma unroll
  for (int k = 0; k < 32; ++k) wk[k] = w[c*32 + k];
  float bc = bias[c];
  float lsum = 0.f, lsq = 0.f;
  float* dst = v + ((long)(b*CO + c))*LSEQ;
  for (int t = tid; t < LSEQ; t += 256){
    float acc = bc;
    #pragma unroll
    for (int k = 0; k < 32; ++k) acc = fmaf(wk[k], row[t + k], acc);
    dst[t] = acc;
    lsum += acc; lsq += acc*acc;
  }
  #pragma unroll
  for (int off = 32; off; off >>= 1){ lsum += __shfl_down(lsum, off); lsq += __shfl_down(lsq, off); }
  if ((tid & 63) == 0){ red[tid>>6] = lsum; red[4 + (tid>>6)] = lsq; }
  __syncthreads();
  if (tid == 0){
    atomicAdd(&stats[64 + b], red[0]+red[1]+red[2]+red[3]);
    atomicAdd(&stats[80 + b], red[4]+red[5]+red[6]+red[7]);
  }
}

// ---------------- Stage B3: GN2 apply + pw2 + encoder -> h (B,HD,LSEQ) ----------------
__global__ void __launch_bounds__(256) k_pw2enc(const float* __restrict__ v,
                                                const float* __restrict__ g2,
                                                const float* __restrict__ b2,
                                                const float* __restrict__ pw2w,
                                                const float* __restrict__ pw2b,
                                                const float* __restrict__ encw,
                                                const float* __restrict__ encb,
                                                const float* __restrict__ stats,
                                                float* __restrict__ h){
  // grid: BB * 32 (t-tiles of 64; last tile = 35)
  int blk = blockIdx.x;
  int b  = blk >> 5;
  int t0 = (blk & 31) << 6;
  int tcnt = min(64, LSEQ - t0);
  __shared__ float vn[CO][64];
  __shared__ float p2[CO*CO];      // transposed [c][o]
  __shared__ float ew[CO*HD];      // [c][d]
  __shared__ float u3[4][CO];
  __shared__ float hout[HD][65];
  int tid = threadIdx.x;
  float m = stats[96 + b], r = stats[112 + b];
  for (int i = tid; i < CO*CO; i += 256){
    int o = i & 31, c = i >> 5;
    p2[c*CO + o] = pw2w[o*CO + c];
  }
  for (int i = tid; i < CO*HD; i += 256) ew[i] = encw[i];
  for (int i = tid; i < CO*64; i += 256){
    int c = i >> 6, t = i & 63;
    float val = 0.f;
    if (t < tcnt) val = v[((long)(b*CO + c))*LSEQ + t0 + t];
    vn[c][t] = (val - m)*r*g2[c] + b2[c];
  }
  __syncthreads();
  int wv = tid >> 6, ln = tid & 63;
  for (int i = 0; i < 16; ++i){
    int tt = wv*16 + i;
    if (ln < CO){
      float acc = pw2b[ln];
      #pragma unroll
      for (int c = 0; c < CO; ++c) acc = fmaf(p2[c*CO + ln], vn[c][tt], acc);
      u3[wv][ln] = acc;   // wave-internal LDS: in-order per wave
    }
    float hacc = encb[ln];
    #pragma unroll
    for (int c = 0; c < CO; ++c) hacc = fmaf(ew[c*HD + ln], u3[wv][c], hacc);
    hout[ln][tt] = hacc;
  }
  __syncthreads();
  for (int i = tid; i < HD*64; i += 256){
    int d = i >> 6, t = i & 63;
    if (t < tcnt) h[((long)(b*HD + d))*LSEQ + t0 + t] = hout[d][t];
  }
}

// ---------------- S4D coefficients for ALL layers ----------------
__global__ void k_coef(const float* __restrict__ log_dt, const float* __restrict__ logA,
                       const float* __restrict__ Aim, const float* __restrict__ Cre,
                       const float* __restrict__ Cim, float* __restrict__ coef){
  // grid: NLAY*HD blocks, 64 threads (lane = n)
  int blk = blockIdx.x;
  int l = blk >> 6, hh = blk & 63;
  int n = threadIdx.x;
  float dt = expf(log_dt[l*HD + hh]);
  int idx = (l*HD + hh)*NST + n;
  float Ar = -expf(logA[idx]);
  float Ai = Aim[idx];
  float dr = Ar*dt, di = Ai*dt;
  float er = expf(dr);
  float wr = er*cosf(di), wi = er*sinf(di);
  float inv = 1.f/(Ar*Ar + Ai*Ai);
  float xr = wr - 1.f, xi = wi;
  float qr = (xr*Ar + xi*Ai)*inv;
  float qi = (xi*Ar - xr*Ai)*inv;
  float cr = Cre[idx], ci = Cim[idx];
  float cdr = cr*qr - ci*qi;
  float cdi = cr*qi + ci*qr;
  float* cl = coef + l*4*HD*NST;
  int hn = hh*NST + n;
  cl[hn]            = wr;
  cl[HD*NST + hn]   = wi;
  cl[2*HD*NST + hn] = cdr;
  cl[3*HD*NST + hn] = cdi;
}

// ---------------- S4D diagonal-SSM scan: y = causal_conv(K, h) ----------------
__global__ void __launch_bounds__(64) k_scan(const float* __restrict__ h,
                                             const float* __restrict__ coef,
                                             int layer, float* __restrict__ y){
  // grid: BB*HD = 1024 blocks of one wave; lane = state index n
  int blk = blockIdx.x;
  int b = blk >> 6, hh = blk & 63;
  int n = threadIdx.x;
  const float* cl = coef + layer*4*HD*NST;
  int hn = hh*NST + n;
  float wr  = cl[hn];
  float wi  = cl[HD*NST + hn];
  float cdr = cl[2*HD*NST + hn];
  float cdi = cl[3*HD*NST + hn];
  const float* u = h + ((long)(b*HD + hh))*LSEQ;
  float* yo      = y + ((long)(b*HD + hh))*LSEQ;
  __shared__ float ub[64];
  __shared__ float db[64*65];
  float sr = 0.f, si = 0.f;
  for (int t0 = 0; t0 < LSEQ; t0 += 64){
    int cnt = min(64, LSEQ - t0);
    if (n < cnt) ub[n] = u[t0 + n];
    __syncthreads();
    #pragma unroll 8
    for (int k = 0; k < cnt; ++k){
      float ut = ub[k];
      float nr = fmaf(wr, sr, ut);
      nr = fmaf(-wi, si, nr);
      float ni = fmaf(wr, si, wi*sr);
      sr = nr; si = ni;
      db[k*65 + n] = fmaf(cdr, sr, -(cdi*si));
    }
    __syncthreads();
    if (n < cnt){
      float acc = 0.f;
      const float* drow = db + n*65;
      #pragma unroll 8
      for (int j = 0; j < 64; ++j) acc += drow[j];
      yo[t0 + n] = 2.f*acc;
    }
    __syncthreads();
  }
}

// ---------------- S4D post: +D*u, GeLU, ow proj, GLU(ch), residual, LN(ch) ----------------
__global__ void __launch_bounds__(256) k_post(const float* __restrict__ y,
                                              float* __restrict__ h,
                                              const float* __restrict__ D,
                                              const float* __restrict__ ow,
                                              const float* __restrict__ ob,
                                              const float* __restrict__ lng,
                                              const float* __restrict__ lnb,
                                              int layer){
  // grid: BB * 32 (t-tiles of 64); wave wv owns timesteps [t0+16wv, t0+16wv+16)
  int blk = blockIdx.x;
  int b  = blk >> 5;
  int t0 = (blk & 31) << 6;
  __shared__ float yv[4][16][64];
  __shared__ float olds[HD][65];
  int tid = threadIdx.x;
  int wv = tid >> 6, ln = tid & 63;
  const float* owp = ow + layer*2*HD*HD;
  const float* obp = ob + layer*2*HD;
  float dl  = D[layer*HD + ln];
  float o1b = obp[ln], o2b = obp[HD + ln];
  float gl = lng[layer*HD + ln], bl = lnb[layer*HD + ln];
  const float* yrow = y + ((long)(b*HD + ln))*LSEQ;
  const float* hrow = h + ((long)(b*HD + ln))*LSEQ;
  float hv[16];
  // Phase A: yv[c] = gelu(y + h*D)  (wave-private LDS slice)
  #pragma unroll
  for (int i = 0; i < 16; ++i){
    int t = t0 + wv*16 + i;
    float yy = 0.f, hh2 = 0.f;
    if (t < LSEQ){ yy = yrow[t]; hh2 = hrow[t]; }
    hv[i] = hh2;
    yv[wv][i][ln] = gelu_(fmaf(hh2, dl, yy));
  }
  // Phase B: o1 = ob[ln] + ow[ln,:] . yv   (row register-resident)
  float row[64];
  #pragma unroll
  for (int c4 = 0; c4 < 16; ++c4){
    float4 r4 = *(const float4*)(owp + ln*HD + c4*4);
    row[c4*4+0]=r4.x; row[c4*4+1]=r4.y; row[c4*4+2]=r4.z; row[c4*4+3]=r4.w;
  }
  float o1s[16];
  #pragma unroll
  for (int i = 0; i < 16; ++i){
    float acc = o1b;
    #pragma unroll
    for (int c4 = 0; c4 < 16; ++c4){
      float4 y4 = *(const float4*)&yv[wv][i][c4*4];
      acc = fmaf(row[c4*4+0], y4.x, acc);
      acc = fmaf(row[c4*4+1], y4.y, acc);
      acc = fmaf(row[c4*4+2], y4.z, acc);
      acc = fmaf(row[c4*4+3], y4.w, acc);
    }
    o1s[i] = acc;
  }
  // Phase C: o2, GLU, residual, LayerNorm over channels
  #pragma unroll
  for (int c4 = 0; c4 < 16; ++c4){
    float4 r4 = *(const float4*)(owp + (HD + ln)*HD + c4*4);
    row[c4*4+0]=r4.x; row[c4*4+1]=r4.y; row[c4*4+2]=r4.z; row[c4*4+3]=r4.w;
  }
  #pragma unroll
  for (int i = 0; i < 16; ++i){
    float acc = o2b;
    #pragma unroll
    for (int c4 = 0; c4 < 16; ++c4){
      float4 y4 = *(const float4*)&yv[wv][i][c4*4];
      acc = fmaf(row[c4*4+0], y4.x, acc);
      acc = fmaf(row[c4*4+1], y4.y, acc);
      acc = fmaf(row[c4*4+2], y4.z, acc);
      acc = fmaf(row[c4*4+3], y4.w, acc);
    }
    float z = o1s[i] * sigm(acc);
    float rres = z + hv[i];
    float s1 = rres, s2 = rres*rres;
    #pragma unroll
    for (int off = 32; off; off >>= 1){ s1 += __shfl_xor(s1, off); s2 += __shfl_xor(s2, off); }
    float mm = s1 * (1.f/64.f);
    float vr = fmaf(-mm, mm, s2*(1.f/64.f));
    float rn = fmaf((rres - mm)*rsqrtf(vr + EPSF), gl, bl);
    olds[ln][wv*16 + i] = rn;
  }
  __syncthreads();
  for (int i2 = tid; i2 < HD*64; i2 += 256){
    int c = i2 >> 6, t = i2 & 63;
    if (t0 + t < LSEQ) h[((long)(b*HD + c))*LSEQ + t0 + t] = olds[c][t];
  }
}

// ---------------- Decoder ----------------
__global__ void __launch_bounds__(256) k_dec(const float* __restrict__ h,
                                             const float* __restrict__ w,
                                             const float* __restrict__ bias,
                                             float* __restrict__ out){
  // grid: BB * 127 (t-tiles of 16; last = 3)
  int blk = blockIdx.x;
  int b  = blk / 127;
  int t0 = (blk % 127) * 16;
  int tcnt = min(16, LSEQ - t0);
  __shared__ float hl[HD*16];
  int tid = threadIdx.x;
  for (int i = tid; i < HD*16; i += 256){
    int d = i >> 4, t = i & 15;
    hl[d*16 + t] = (t < tcnt) ? h[((long)(b*HD + d))*LSEQ + t0 + t] : 0.f;
  }
  __syncthreads();
  for (int task = tid; task < 16*160; task += 256){
    int t = task / 160, o4 = task % 160;
    if (t >= tcnt) continue;
    float4 acc = *(const float4*)(bias + o4*4);
    #pragma unroll 8
    for (int d = 0; d < HD; ++d){
      float hv = hl[d*16 + t];
      float4 w4 = *(const float4*)(w + d*DOUT + o4*4);
      acc.x = fmaf(hv, w4.x, acc.x);
      acc.y = fmaf(hv, w4.y, acc.y);
      acc.z = fmaf(hv, w4.z, acc.z);
      acc.w = fmaf(hv, w4.w, acc.w);
    }
    *(float4*)(out + ((long)(b*LSEQ + t0 + t))*DOUT + o4*4) = acc;
  }
}

extern "C" void kernel_launch(void* const* d_in, const int* in_sizes, int n_in,
                              void* d_out, int out_size, void* d_ws, size_t ws_size,
                              hipStream_t stream){
  const float* x     = (const float*)d_in[0];
  const float* pw1_w = (const float*)d_in[1];
  const float* pw1_b = (const float*)d_in[2];
  const float* gn1_g = (const float*)d_in[3];
  const float* gn1_b = (const float*)d_in[4];
  const float* dw_w  = (const float*)d_in[5];
  const float* dw_b  = (const float*)d_in[6];
  const float* gn2_g = (const float*)d_in[7];
  const float* gn2_b = (const float*)d_in[8];
  const float* pw2_w = (const float*)d_in[9];
  const float* pw2_b = (const float*)d_in[10];
  const float* enc_w = (const float*)d_in[11];
  const float* enc_b = (const float*)d_in[12];
  const float* log_dt= (const float*)d_in[13];
  const float* logA  = (const float*)d_in[14];
  const float* Aim   = (const float*)d_in[15];
  const float* Cre   = (const float*)d_in[16];
  const float* Cim   = (const float*)d_in[17];
  const float* Dp    = (const float*)d_in[18];
  const float* owp   = (const float*)d_in[19];
  const float* obp   = (const float*)d_in[20];
  const float* lng   = (const float*)d_in[21];
  const float* lnb   = (const float*)d_in[22];
  const float* dec_w = (const float*)d_in[23];
  const float* dec_b = (const float*)d_in[24];
  float* out = (float*)d_out;

  float* ws   = (float*)d_ws;
  float* u1   = ws;                    // 2,097,152 floats (reused as ybuf later)
  float* u2   = u1 + 2097152;          // 1,048,576
  float* vv   = u2 + 1048576;          // 1,033,728
  float* hbuf = vv + 1033728;          // 2,067,456
  float* coef = hbuf + 2067456;        // 131,072
  float* stats= coef + 131072;         // 128
  float* ybuf = u1;                    // u1 dead after k_glu_silu

  hipMemsetAsync(stats, 0, 128*sizeof(float), stream);
  k_coef<<<NLAY*HD, 64, 0, stream>>>(log_dt, logA, Aim, Cre, Cim, coef);
  k_pw1<<<BB*64, 256, 0, stream>>>(x, pw1_w, pw1_b, u1, stats);
  k_gnstat<<<1, 64, 0, stream>>>(stats, 0, (float)(CO*TFULL));
  k_glu_silu<<<BB*32, 256, 0, stream>>>(u1, gn1_g, gn1_b, stats, u2);
  k_dconv<<<BB*CO, 256, 0, stream>>>(u2, dw_w, dw_b, vv, stats);
  k_gnstat<<<1, 64, 0, stream>>>(stats, 1, (float)(CO*LSEQ));
  k_pw2enc<<<BB*32, 256, 0, stream>>>(vv, gn2_g, gn2_b, pw2_w, pw2_b, enc_w, enc_b, stats, hbuf);
  for (int l = 0; l < NLAY; ++l){
    k_scan<<<BB*HD, 64, 0, stream>>>(hbuf, coef, l, ybuf);
    k_post<<<BB*32, 256, 0, stream>>>(ybuf, hbuf, Dp, owp, obp, lng, lnb, l);
  }
  k_dec<<<BB*127, 256, 0, stream>>>(hbuf, dec_w, dec_b, out);
}

// Round 2
// 1208.861 us; speedup vs baseline: 1.3048x; 1.3048x over previous
//
#include <hip/hip_runtime.h>
#include <math.h>

#define BB   16
#define TFULL 4096
#define T2   2048
#define LSEQ 2019
#define HSTR 2048
#define CIN  64
#define CO   32
#define HD   64
#define NST  64
#define NLAY 8
#define DOUT 640
#define EPSF 1e-5f
#define NCH  32   // chunks per sequence
#define CHL  64   // chunk length

static __device__ __forceinline__ float sigm(float x){ return 1.f/(1.f + __expf(-x)); }
static __device__ __forceinline__ float gelu_(float x){ return 0.5f*x*(1.f + erff(x*0.7071067811865475f)); }

// ---------------- Stage A: pw1 conv + GN1 partial stats ----------------
__global__ void __launch_bounds__(256) k_pw1(const float* __restrict__ x,
                                             const float* __restrict__ w,
                                             const float* __restrict__ bias,
                                             float* __restrict__ u1,
                                             float* __restrict__ stats){
  int blk = blockIdx.x;
  int b  = blk >> 6;
  int t0 = (blk & 63) << 6;
  __shared__ float xs[CIN][64];
  __shared__ float wsm[CO*CIN];
  __shared__ float red[8];
  int tid = threadIdx.x;
  for (int i = tid; i < CIN*64; i += 256){
    int c = i >> 6, t = i & 63;
    xs[c][t] = x[((long)(b*CIN + c))*TFULL + t0 + t];
  }
  for (int i = tid; i < CO*CIN; i += 256) wsm[i] = w[i];
  __syncthreads();
  int t  = tid & 63;
  int o0 = tid >> 6;
  float lsum = 0.f, lsq = 0.f;
  for (int o = o0; o < CO; o += 4){
    float acc = bias[o];
    #pragma unroll
    for (int c = 0; c < CIN; ++c) acc = fmaf(wsm[o*CIN + c], xs[c][t], acc);
    u1[((long)(b*CO + o))*TFULL + t0 + t] = acc;
    lsum += acc; lsq += acc*acc;
  }
  #pragma unroll
  for (int off = 32; off; off >>= 1){ lsum += __shfl_down(lsum, off); lsq += __shfl_down(lsq, off); }
  if ((tid & 63) == 0){ red[tid>>6] = lsum; red[4 + (tid>>6)] = lsq; }
  __syncthreads();
  if (tid == 0){
    atomicAdd(&stats[b],      red[0]+red[1]+red[2]+red[3]);
    atomicAdd(&stats[16 + b], red[4]+red[5]+red[6]+red[7]);
  }
}

__global__ void k_gnstat(float* __restrict__ stats, int which, float cnt){
  int b = threadIdx.x;
  if (b < BB){
    int o = which * 64;
    float m = stats[o + b] / cnt;
    float v = stats[o + 16 + b] / cnt - m*m;
    stats[o + 32 + b] = m;
    stats[o + 48 + b] = rsqrtf(v + EPSF);
  }
}

// ---------------- Stage A3: GN1 apply + GLU(time) + SiLU ----------------
__global__ void __launch_bounds__(256) k_glu_silu(const float* __restrict__ u1,
                                                  const float* __restrict__ g,
                                                  const float* __restrict__ bb,
                                                  const float* __restrict__ stats,
                                                  float* __restrict__ u2){
  int blk = blockIdx.x;
  int b  = blk >> 5;
  int t0 = (blk & 31) << 6;
  float m = stats[32 + b], r = stats[48 + b];
  int tid = threadIdx.x;
  int t = t0 + (tid & 63);
  for (int c = tid >> 6; c < CO; c += 4){
    long base = ((long)(b*CO + c))*TFULL;
    float a  = u1[base + t];
    float bv = u1[base + t + T2];
    float gc = g[c], bc = bb[c];
    a  = (a  - m)*r*gc + bc;
    bv = (bv - m)*r*gc + bc;
    float z = a * sigm(bv);
    z = z * sigm(z);
    u2[((long)(b*CO + c))*T2 + t] = z;
  }
}

// ---------------- Stage B1: depthwise conv (K=32, pad 1) + GN2 partial stats ----------------
__global__ void __launch_bounds__(256) k_dconv(const float* __restrict__ u2,
                                               const float* __restrict__ w,
                                               const float* __restrict__ bias,
                                               float* __restrict__ v,
                                               float* __restrict__ stats){
  int blk = blockIdx.x;
  int b = blk >> 5, c = blk & 31;
  __shared__ float row[T2 + 2];
  __shared__ float red[8];
  int tid = threadIdx.x;
  if (tid == 0){ row[0] = 0.f; row[T2 + 1] = 0.f; }
  const float* src = u2 + ((long)(b*CO + c))*T2;
  for (int i = tid; i < T2; i += 256) row[1 + i] = src[i];
  __syncthreads();
  float wk[32];
  #pragma unroll
  for (int k = 0; k < 32; ++k) wk[k] = w[c*32 + k];
  float bc = bias[c];
  float lsum = 0.f, lsq = 0.f;
  float* dst = v + ((long)(b*CO + c))*LSEQ;
  for (int t = tid; t < LSEQ; t += 256){
    float acc = bc;
    #pragma unroll
    for (int k = 0; k < 32; ++k) acc = fmaf(wk[k], row[t + k], acc);
    dst[t] = acc;
    lsum += acc; lsq += acc*acc;
  }
  #pragma unroll
  for (int off = 32; off; off >>= 1){ lsum += __shfl_down(lsum, off); lsq += __shfl_down(lsq, off); }
  if ((tid & 63) == 0){ red[tid>>6] = lsum; red[4 + (tid>>6)] = lsq; }
  __syncthreads();
  if (tid == 0){
    atomicAdd(&stats[64 + b], red[0]+red[1]+red[2]+red[3]);
    atomicAdd(&stats[80 + b], red[4]+red[5]+red[6]+red[7]);
  }
}

// ---------------- Stage B3: GN2 apply + pw2 + encoder -> h (B,HD,HSTR) ----------------
__global__ void __launch_bounds__(256) k_pw2enc(const float* __restrict__ v,
                                                const float* __restrict__ g2,
                                                const float* __restrict__ b2,
                                                const float* __restrict__ pw2w,
                                                const float* __restrict__ pw2b,
                                                const float* __restrict__ encw,
                                                const float* __restrict__ encb,
                                                const float* __restrict__ stats,
                                                float* __restrict__ h){
  int blk = blockIdx.x;
  int b  = blk >> 5;
  int t0 = (blk & 31) << 6;
  int tcnt = min(64, LSEQ - t0);
  __shared__ float vn[CO][64];
  __shared__ float p2[CO*CO];
  __shared__ float ew[CO*HD];
  __shared__ float u3[4][CO];
  __shared__ float hout[HD][65];
  int tid = threadIdx.x;
  float m = stats[96 + b], r = stats[112 + b];
  for (int i = tid; i < CO*CO; i += 256){
    int o = i & 31, c = i >> 5;
    p2[c*CO + o] = pw2w[o*CO + c];
  }
  for (int i = tid; i < CO*HD; i += 256) ew[i] = encw[i];
  for (int i = tid; i < CO*64; i += 256){
    int c = i >> 6, t = i & 63;
    float val = 0.f;
    if (t < tcnt) val = v[((long)(b*CO + c))*LSEQ + t0 + t];
    vn[c][t] = (val - m)*r*g2[c] + b2[c];
  }
  __syncthreads();
  int wv = tid >> 6, ln = tid & 63;
  for (int i = 0; i < 16; ++i){
    int tt = wv*16 + i;
    if (ln < CO){
      float acc = pw2b[ln];
      #pragma unroll
      for (int c = 0; c < CO; ++c) acc = fmaf(p2[c*CO + ln], vn[c][tt], acc);
      u3[wv][ln] = acc;
    }
    float hacc = encb[ln];
    #pragma unroll
    for (int c = 0; c < CO; ++c) hacc = fmaf(ew[c*HD + ln], u3[wv][c], hacc);
    hout[ln][tt] = hacc;
  }
  __syncthreads();
  for (int i = tid; i < HD*64; i += 256){
    int d = i >> 6, t = i & 63;
    if (t < tcnt) h[((long)(b*HD + d))*HSTR + t0 + t] = hout[d][t];
  }
}

// ---------------- S4D coefficients for ALL layers ----------------
__global__ void k_coef(const float* __restrict__ log_dt, const float* __restrict__ logA,
                       const float* __restrict__ Aim, const float* __restrict__ Cre,
                       const float* __restrict__ Cim, float* __restrict__ coef){
  int blk = blockIdx.x;
  int l = blk >> 6, hh = blk & 63;
  int n = threadIdx.x;
  float dt = expf(log_dt[l*HD + hh]);
  int idx = (l*HD + hh)*NST + n;
  float Ar = -expf(logA[idx]);
  float Ai = Aim[idx];
  float dr = Ar*dt, di = Ai*dt;
  float er = expf(dr);
  float wr = er*cosf(di), wi = er*sinf(di);
  float inv = 1.f/(Ar*Ar + Ai*Ai);
  float xr = wr - 1.f, xi = wi;
  float qr = (xr*Ar + xi*Ai)*inv;
  float qi = (xi*Ar - xr*Ai)*inv;
  float cr = Cre[idx], ci = Cim[idx];
  float cdr = cr*qr - ci*qi;
  float cdi = cr*qi + ci*qr;
  float* cl = coef + l*4*HD*NST;
  int hn = hh*NST + n;
  cl[hn]            = wr;
  cl[HD*NST + hn]   = wi;
  cl[2*HD*NST + hn] = cdr;
  cl[3*HD*NST + hn] = cdi;
}

// ---------------- S4D chunk-parallel scan, one kernel per layer ----------------
// Block = 256 threads (4 waves), one (b,h) row. Chunks of 64, 32 chunks.
// Phase1: wave q computes v_c = sum_j w^{63-j} u[j] for its 8 chunks (ILP-8).
// Phase2: wave 0 scans chunk states: S_in[c]; s <- w^64 s + v_c.
// Phase3: y[t0+i] = sum_j K[i-j] u[t0+j]  +  Re( sum_n E2[n][i+1] * S_in[n] )
//   with E2[n][k] = 2*cd_n*w_n^k (in LDS), K[d] = sum_n E2[n][d].re.
__global__ void __launch_bounds__(256) k_s4d(const float* __restrict__ h,
                                             const float* __restrict__ coef,
                                             int layer, float* __restrict__ y){
  int blk = blockIdx.x;
  int b = blk >> 6, hh = blk & 63;
  __shared__ float u_s[2048];
  __shared__ float E2[64*130];     // row n at n*130, 65 float2 entries (k=0..64)
  __shared__ float S_s[NCH*128];   // [c][n] float2
  __shared__ float Kpad[128];      // [0..63]=0, [64+d]=K[d]
  int tid = threadIdx.x;
  int n = tid & 63;                // lane id
  int q = tid >> 6;                // wave id
  const float* cl = coef + layer*4*HD*NST;
  int hn = hh*NST + n;
  float wr  = cl[hn];
  float wi  = cl[HD*NST + hn];
  float cdr = cl[2*HD*NST + hn];
  float cdi = cl[3*HD*NST + hn];
  const float* up = h + ((long)(b*HD + hh))*HSTR;

  // ---- stage u (zero-pad tail) ----
  {
    int base = tid*8;
    if (base + 8 <= LSEQ){
      float4 a0 = *(const float4*)(up + base);
      float4 a1 = *(const float4*)(up + base + 4);
      *(float4*)&u_s[base]     = a0;
      *(float4*)&u_s[base + 4] = a1;
    } else {
      #pragma unroll
      for (int k = 0; k < 8; ++k){
        int t = base + k;
        u_s[t] = (t < LSEQ) ? up[t] : 0.f;
      }
    }
  }
  if (tid < 64) Kpad[tid] = 0.f;

  // ---- build E2 rows: thread (n,q) fills k in [16q, 16q+15] (q==3: +16 incl k=64) ----
  {
    // w^16 by 4 squarings
    float ar = wr, ai = wi;
    #pragma unroll
    for (int s = 0; s < 4; ++s){ float t2 = ar*ar - ai*ai; ai = 2.f*ar*ai; ar = t2; }
    float pr = 1.f, pi = 0.f;
    for (int k = 0; k < q; ++k){ float t2 = pr*ar - pi*ai; pi = pr*ai + pi*ar; pr = t2; }
    float* rowp = &E2[n*130 + 2*(q*16)];
    int cnt = (q == 3) ? 17 : 16;
    for (int k = 0; k < cnt; ++k){
      rowp[2*k]   = 2.f*(cdr*pr - cdi*pi);
      rowp[2*k+1] = 2.f*(cdr*pi + cdi*pr);
      float t2 = pr*wr - pi*wi; pi = pr*wi + pi*wr; pr = t2;
    }
  }
  __syncthreads();

  // ---- phase 1: per-chunk decayed input sums (wave q owns chunks q*8..q*8+7) ----
  int cbase = q*8;
  {
    float vr[8], vi[8];
    #pragma unroll
    for (int c8 = 0; c8 < 8; ++c8){ vr[c8] = 0.f; vi[c8] = 0.f; }
    for (int j = 0; j < 64; ++j){
      #pragma unroll
      for (int c8 = 0; c8 < 8; ++c8){
        float uj = u_s[(cbase + c8)*64 + j];
        float nr = fmaf(wr, vr[c8], fmaf(-wi, vi[c8], uj));
        float ni = fmaf(wr, vi[c8], wi*vr[c8]);
        vr[c8] = nr; vi[c8] = ni;
      }
    }
    #pragma unroll
    for (int c8 = 0; c8 < 8; ++c8){
      S_s[(cbase + c8)*128 + 2*n]     = vr[c8];
      S_s[(cbase + c8)*128 + 2*n + 1] = vi[c8];
    }
  }
  __syncthreads();

  // ---- phase 2 (wave 0): K taps + chunk-state scan ----
  if (q == 0){
    float ks = 0.f;
    for (int nn = 0; nn < 64; ++nn) ks += E2[nn*130 + 2*n];  // lane's d = n
    Kpad[64 + n] = ks;
    // w^64 by 6 squarings
    float ar = wr, ai = wi;
    #pragma unroll
    for (int s = 0; s < 6; ++s){ float t2 = ar*ar - ai*ai; ai = 2.f*ar*ai; ar = t2; }
    float sr = 0.f, si = 0.f;
    for (int c = 0; c < NCH; ++c){
      float vr2 = S_s[c*128 + 2*n], vi2 = S_s[c*128 + 2*n + 1];
      S_s[c*128 + 2*n]     = sr;   // S_in[c]
      S_s[c*128 + 2*n + 1] = si;
      float nr = fmaf(ar, sr, fmaf(-ai, si, vr2));
      float ni = fmaf(ar, si, fmaf(ai, sr, vi2));
      sr = nr; si = ni;
    }
  }
  __syncthreads();

  // ---- phase 3: outputs (wave q, its 8 chunks; lane = i) ----
  float* yo = y + ((long)(b*HD + hh))*HSTR;
  int i = n;
  for (int c8 = 0; c8 < 8; ++c8){
    int c = cbase + c8;
    const float* ub = &u_s[c*64];
    float acc = 0.f;
    #pragma unroll 8
    for (int j = 0; j < 64; ++j)
      acc = fmaf(Kpad[64 + i - j], ub[j], acc);
    const float* Sc = &S_s[c*128];
    #pragma unroll 8
    for (int nn = 0; nn < 64; ++nn){
      float2 e  = *(const float2*)&E2[nn*130 + 2*(i + 1)];
      float2 sv = *(const float2*)&Sc[2*nn];
      acc = fmaf(e.x, sv.x, fmaf(-e.y, sv.y, acc));
    }
    int t = c*64 + i;
    if (t < LSEQ) yo[t] = acc;
  }
}

// ---------------- S4D post: +D*u, GeLU, ow proj, GLU(ch), residual, LN(ch) ----------------
__global__ void __launch_bounds__(256) k_post(const float* __restrict__ y,
                                              float* __restrict__ h,
                                              const float* __restrict__ D,
                                              const float* __restrict__ ow,
                                              const float* __restrict__ ob,
                                              const float* __restrict__ lng,
                                              const float* __restrict__ lnb,
                                              int layer){
  int blk = blockIdx.x;
  int b  = blk >> 5;
  int t0 = (blk & 31) << 6;
  __shared__ float yv[4][16][64];
  __shared__ float olds[HD][65];
  int tid = threadIdx.x;
  int wv = tid >> 6, ln = tid & 63;
  const float* owp = ow + layer*2*HD*HD;
  const float* obp = ob + layer*2*HD;
  float dl  = D[layer*HD + ln];
  float o1b = obp[ln], o2b = obp[HD + ln];
  float gl = lng[layer*HD + ln], bl = lnb[layer*HD + ln];
  const float* yrow = y + ((long)(b*HD + ln))*HSTR;
  const float* hrow = h + ((long)(b*HD + ln))*HSTR;
  float hv[16];
  #pragma unroll
  for (int i = 0; i < 16; ++i){
    int t = t0 + wv*16 + i;
    float yy = 0.f, hh2 = 0.f;
    if (t < LSEQ){ yy = yrow[t]; hh2 = hrow[t]; }
    hv[i] = hh2;
    yv[wv][i][ln] = gelu_(fmaf(hh2, dl, yy));
  }
  float row[64];
  #pragma unroll
  for (int c4 = 0; c4 < 16; ++c4){
    float4 r4 = *(const float4*)(owp + ln*HD + c4*4);
    row[c4*4+0]=r4.x; row[c4*4+1]=r4.y; row[c4*4+2]=r4.z; row[c4*4+3]=r4.w;
  }
  float o1s[16];
  #pragma unroll
  for (int i = 0; i < 16; ++i){
    float acc = o1b;
    #pragma unroll
    for (int c4 = 0; c4 < 16; ++c4){
      float4 y4 = *(const float4*)&yv[wv][i][c4*4];
      acc = fmaf(row[c4*4+0], y4.x, acc);
      acc = fmaf(row[c4*4+1], y4.y, acc);
      acc = fmaf(row[c4*4+2], y4.z, acc);
      acc = fmaf(row[c4*4+3], y4.w, acc);
    }
    o1s[i] = acc;
  }
  #pragma unroll
  for (int c4 = 0; c4 < 16; ++c4){
    float4 r4 = *(const float4*)(owp + (HD + ln)*HD + c4*4);
    row[c4*4+0]=r4.x; row[c4*4+1]=r4.y; row[c4*4+2]=r4.z; row[c4*4+3]=r4.w;
  }
  #pragma unroll
  for (int i = 0; i < 16; ++i){
    float acc = o2b;
    #pragma unroll
    for (int c4 = 0; c4 < 16; ++c4){
      float4 y4 = *(const float4*)&yv[wv][i][c4*4];
      acc = fmaf(row[c4*4+0], y4.x, acc);
      acc = fmaf(row[c4*4+1], y4.y, acc);
      acc = fmaf(row[c4*4+2], y4.z, acc);
      acc = fmaf(row[c4*4+3], y4.w, acc);
    }
    float z = o1s[i] * sigm(acc);
    float rres = z + hv[i];
    float s1 = rres, s2 = rres*rres;
    #pragma unroll
    for (int off = 32; off; off >>= 1){ s1 += __shfl_xor(s1, off); s2 += __shfl_xor(s2, off); }
    float mm = s1 * (1.f/64.f);
    float vr = fmaf(-mm, mm, s2*(1.f/64.f));
    float rn = fmaf((rres - mm)*rsqrtf(vr + EPSF), gl, bl);
    olds[ln][wv*16 + i] = rn;
  }
  __syncthreads();
  for (int i2 = tid; i2 < HD*64; i2 += 256){
    int c = i2 >> 6, t = i2 & 63;
    if (t0 + t < LSEQ) h[((long)(b*HD + c))*HSTR + t0 + t] = olds[c][t];
  }
}

// ---------------- Decoder: register-blocked, weight-reuse GEMM ----------------
__global__ void __launch_bounds__(320) k_dec(const float* __restrict__ h,
                                             const float* __restrict__ w,
                                             const float* __restrict__ bias,
                                             float* __restrict__ out){
  // grid: BB * 64 t-tiles of 32. Block 320: thread = (o4 in 0..159, th in 0..1)
  int blk = blockIdx.x;
  int b  = blk >> 6;
  int t0 = (blk & 63) << 5;
  __shared__ float hl[HD][32];
  int tid = threadIdx.x;
  for (int i = tid; i < HD*32; i += 320){
    int d = i >> 5, t = i & 31;
    int tt = t0 + t;
    hl[d][t] = (tt < LSEQ) ? h[((long)(b*HD + d))*HSTR + tt] : 0.f;
  }
  __syncthreads();
  int o4 = tid % 160, th = tid / 160;
  int tb = th * 16;
  float4 acc[16];
  const float4 b4 = *(const float4*)(bias + o4*4);
  #pragma unroll
  for (int i = 0; i < 16; ++i) acc[i] = b4;
  const float* wp = w + o4*4;
  for (int d = 0; d < HD; ++d){
    float4 w4 = *(const float4*)(wp + (long)d*DOUT);
    #pragma unroll
    for (int ii = 0; ii < 4; ++ii){
      float4 h4 = *(const float4*)&hl[d][tb + ii*4];
      float hvv[4] = {h4.x, h4.y, h4.z, h4.w};
      #pragma unroll
      for (int jj = 0; jj < 4; ++jj){
        int i = ii*4 + jj;
        acc[i].x = fmaf(hvv[jj], w4.x, acc[i].x);
        acc[i].y = fmaf(hvv[jj], w4.y, acc[i].y);
        acc[i].z = fmaf(hvv[jj], w4.z, acc[i].z);
        acc[i].w = fmaf(hvv[jj], w4.w, acc[i].w);
      }
    }
  }
  #pragma unroll
  for (int i = 0; i < 16; ++i){
    int t = t0 + tb + i;
    if (t < LSEQ) *(float4*)(out + ((long)(b*LSEQ) + t)*DOUT + o4*4) = acc[i];
  }
}

extern "C" void kernel_launch(void* const* d_in, const int* in_sizes, int n_in,
                              void* d_out, int out_size, void* d_ws, size_t ws_size,
                              hipStream_t stream){
  const float* x     = (const float*)d_in[0];
  const float* pw1_w = (const float*)d_in[1];
  const float* pw1_b = (const float*)d_in[2];
  const float* gn1_g = (const float*)d_in[3];
  const float* gn1_b = (const float*)d_in[4];
  const float* dw_w  = (const float*)d_in[5];
  const float* dw_b  = (const float*)d_in[6];
  const float* gn2_g = (const float*)d_in[7];
  const float* gn2_b = (const float*)d_in[8];
  const float* pw2_w = (const float*)d_in[9];
  const float* pw2_b = (const float*)d_in[10];
  const float* enc_w = (const float*)d_in[11];
  const float* enc_b = (const float*)d_in[12];
  const float* log_dt= (const float*)d_in[13];
  const float* logA  = (const float*)d_in[14];
  const float* Aim   = (const float*)d_in[15];
  const float* Cre   = (const float*)d_in[16];
  const float* Cim   = (const float*)d_in[17];
  const float* Dp    = (const float*)d_in[18];
  const float* owp   = (const float*)d_in[19];
  const float* obp   = (const float*)d_in[20];
  const float* lng   = (const float*)d_in[21];
  const float* lnb   = (const float*)d_in[22];
  const float* dec_w = (const float*)d_in[23];
  const float* dec_b = (const float*)d_in[24];
  float* out = (float*)d_out;

  float* ws   = (float*)d_ws;
  float* u1   = ws;                    // 2,097,152 floats (reused as ybuf)
  float* u2   = u1 + 2097152;          // 1,048,576
  float* vv   = u2 + 1048576;          // 1,033,728
  float* hbuf = vv + 1033728;          // 2,097,152 (stride-2048 rows)
  float* coef = hbuf + 2097152;        // 131,072
  float* stats= coef + 131072;         // 128
  float* ybuf = u1;

  hipMemsetAsync(stats, 0, 128*sizeof(float), stream);
  k_coef<<<NLAY*HD, 64, 0, stream>>>(log_dt, logA, Aim, Cre, Cim, coef);
  k_pw1<<<BB*64, 256, 0, stream>>>(x, pw1_w, pw1_b, u1, stats);
  k_gnstat<<<1, 64, 0, stream>>>(stats, 0, (float)(CO*TFULL));
  k_glu_silu<<<BB*32, 256, 0, stream>>>(u1, gn1_g, gn1_b, stats, u2);
  k_dconv<<<BB*CO, 256, 0, stream>>>(u2, dw_w, dw_b, vv, stats);
  k_gnstat<<<1, 64, 0, stream>>>(stats, 1, (float)(CO*LSEQ));
  k_pw2enc<<<BB*32, 256, 0, stream>>>(vv, gn2_g, gn2_b, pw2_w, pw2_b, enc_w, enc_b, stats, hbuf);
  for (int l = 0; l < NLAY; ++l){
    k_s4d<<<BB*HD, 256, 0, stream>>>(hbuf, coef, l, ybuf);
    k_post<<<BB*32, 256, 0, stream>>>(ybuf, hbuf, Dp, owp, obp, lng, lnb, l);
  }
  k_dec<<<BB*64, 320, 0, stream>>>(hbuf, dec_w, dec_b, out);
}